// Round 3
// baseline (1615.065 us; speedup 1.0000x reference)
//
#include <hip/hip_runtime.h>
#include <cstdint>

#define S_   2048
#define NH_  32

typedef short  short8  __attribute__((ext_vector_type(8)));
typedef float  floatx4 __attribute__((ext_vector_type(4)));
typedef unsigned int uintx2 __attribute__((ext_vector_type(2)));
typedef unsigned short u16;
typedef unsigned int   u32;

__device__ inline u32 pk_bf16(float a, float b) {
  u32 ua = __builtin_bit_cast(u32, a) + 0x8000u;
  u32 ub = __builtin_bit_cast(u32, b) + 0x8000u;
  return __builtin_amdgcn_perm(ub, ua, 0x07060302u);
}
__device__ inline u16 f32_bf16(float a) {
  return (u16)((__builtin_bit_cast(u32, a) + 0x8000u) >> 16);
}
__device__ inline void gld16(const u16* g, u16* l) {
  __builtin_amdgcn_global_load_lds((const __attribute__((address_space(1))) void*)g,
                                   (__attribute__((address_space(3))) void*)l, 16, 0, 0);
}

// fused fp32->bf16: hs (16384 blk) + Wq (16384 blk) + Wk (4096 blk)
__global__ __launch_bounds__(256)
void cvt3(const float* __restrict__ hs, const float* __restrict__ wq,
          const float* __restrict__ wk, u32* __restrict__ hsB, u32* __restrict__ w1) {
  const int bid = blockIdx.x;
  const float* src; u32* dst; int lb;
  if (bid < 16384)      { src = hs; dst = hsB;           lb = bid; }
  else if (bid < 32768) { src = wq; dst = w1;            lb = bid - 16384; }
  else                  { src = wk; dst = w1 + 8388608;  lb = bid - 32768; }
  const int idx = lb * 256 + threadIdx.x;
  floatx4 v = ((const floatx4*)src)[idx];
  uintx2 o; o[0] = pk_bf16(v[0], v[1]); o[1] = pk_bf16(v[2], v[3]);
  ((uintx2*)dst)[idx] = o;
}

__global__ __launch_bounds__(256)
void cvt1(const float* __restrict__ in, u32* __restrict__ out) {
  const int idx = blockIdx.x * 256 + threadIdx.x;
  floatx4 v = ((const floatx4*)in)[idx];
  uintx2 o; o[0] = pk_bf16(v[0], v[1]); o[1] = pk_bf16(v[2], v[3]);
  ((uintx2*)out)[idx] = o;
}

// bf16 transpose: in [4096 x 1024] -> out [1024 x 4096]. grid (16, 64).
__global__ __launch_bounds__(256)
void transp(const u16* __restrict__ in, u16* __restrict__ out) {
  __shared__ u16 T[64 * 66];
  const int tid = threadIdx.x, wave = tid >> 6, j = tid & 63;
  const int c0 = blockIdx.x * 64, r0 = blockIdx.y * 64;
#pragma unroll
  for (int it = 0; it < 16; it++) {
    const int i = it * 4 + wave;
    T[i * 66 + j] = in[(size_t)(r0 + i) * 1024 + c0 + j];
  }
  __syncthreads();
#pragma unroll
  for (int it = 0; it < 16; it++) {
    const int i = it * 4 + wave;
    out[(size_t)(c0 + i) * 4096 + r0 + j] = T[j * 66 + i];
  }
}

// Y = A(M x 4096) @ B(N x 4096)^T bf16, 128x128 tile, m97-style staging.
// MODE 0: N=5120, col<4096 -> RoPE+scale -> Y0 (ld 4096); col>=4096 -> RoPE -> Y1 (ld 1024)
// MODE 1: plain bf16 -> Y0 (ld N)
// MODE 2: fp32 -> Y0 (ld N)
template<int MODE>
__global__ __launch_bounds__(256)
void gemm128(const u16* __restrict__ A, const u16* __restrict__ B,
             void* __restrict__ Y0, void* __restrict__ Y1, int N,
             const float* __restrict__ cosT, const float* __restrict__ sinT)
{
  constexpr int K = 4096;
  __shared__ __align__(16) u16 As[128 * 32];
  __shared__ __align__(16) u16 Bs[128 * 32];
  const int bn = blockIdx.x * 128, bm = blockIdx.y * 128;
  const int tid = threadIdx.x, wave = tid >> 6, lane = tid & 63;
  const int l15 = lane & 15, quad = lane >> 4;
  const int wr = (wave & 1) * 64, wc = (wave >> 1) * 64;

  const int crow = lane >> 2;
  const int ckb  = (lane & 3) ^ ((lane >> 3) & 3);
  const int q0 = wave * 2, q1 = q0 + 1;
  const u16* gA0 = A + (size_t)(bm + q0 * 16 + crow) * K + ckb * 8;
  const u16* gA1 = A + (size_t)(bm + q1 * 16 + crow) * K + ckb * 8;
  const u16* gB0 = B + (size_t)(bn + q0 * 16 + crow) * K + ckb * 8;
  const u16* gB1 = B + (size_t)(bn + q1 * 16 + crow) * K + ckb * 8;
  u16* lA0 = As + q0 * 512;
  u16* lA1 = As + q1 * 512;
  u16* lB0 = Bs + q0 * 512;
  u16* lB1 = Bs + q1 * 512;

  const int slot = quad ^ ((l15 >> 1) & 3);
  int aoff[4], boff[4];
#pragma unroll
  for (int t = 0; t < 4; t++) {
    aoff[t] = (wr + t * 16 + l15) * 32 + slot * 8;
    boff[t] = (wc + t * 16 + l15) * 32 + slot * 8;
  }

  floatx4 acc[4][4] = {};

  for (int k0 = 0; k0 < K; k0 += 32) {
    __syncthreads();
    gld16(gA0 + k0, lA0);
    gld16(gA1 + k0, lA1);
    gld16(gB0 + k0, lB0);
    gld16(gB1 + k0, lB1);
    __syncthreads();

    short8 af[4], bf[4];
#pragma unroll
    for (int t = 0; t < 4; t++) af[t] = *(const short8*)(As + aoff[t]);
#pragma unroll
    for (int t = 0; t < 4; t++) bf[t] = *(const short8*)(Bs + boff[t]);
#pragma unroll
    for (int mt = 0; mt < 4; mt++)
#pragma unroll
      for (int nt = 0; nt < 4; nt++)
        acc[mt][nt] = __builtin_amdgcn_mfma_f32_16x16x32_bf16(af[mt], bf[nt], acc[mt][nt], 0, 0, 0);
  }

#pragma unroll
  for (int mt = 0; mt < 4; mt++) {
#pragma unroll
    for (int nt = 0; nt < 4; nt++) {
      const int col = bn + wc + nt * 16 + l15;
#pragma unroll
      for (int r = 0; r < 4; r++) {
        const int row = bm + wr + mt * 16 + quad * 4 + r;
        float v = acc[mt][nt][r];
        if (MODE == 0) {
          float other = __shfl_xor(v, 1, 64);
          const int pos = row & (S_ - 1);
          const int i   = (col & 127) >> 1;
          const float c  = cosT[pos * 64 + i];
          const float sn = sinT[pos * 64 + i];
          v = (lane & 1) ? (other * sn + v * c) : (v * c - other * sn);
          if (col < 4096) {
            ((u16*)Y0)[(size_t)row * 4096 + col] = f32_bf16(v * 0.08838834764831845f);
          } else {
            ((u16*)Y1)[(size_t)row * 1024 + (col - 4096)] = f32_bf16(v);
          }
        } else if (MODE == 1) {
          ((u16*)Y0)[(size_t)row * N + col] = f32_bf16(v);
        } else {
          ((float*)Y0)[(size_t)row * N + col] = v;
        }
      }
    }
  }
}

// Barrier-free MFMA flash attention. grid (S/64, B*NH), 4 waves, 16 q-rows/wave.
// K and V^T fragments loaded DIRECTLY from global (L1-shared across waves);
// only the per-wave P C->A layout round-trip uses LDS. C written in-place to Q.
__global__ __launch_bounds__(256)
void flash2(u16* __restrict__ Q, const u16* __restrict__ Kg, const u16* __restrict__ Vtg)
{
  __shared__ u16 Ps[4 * 16 * 72];

  const int tid = threadIdx.x, wave = tid >> 6, lane = tid & 63;
  const int l15 = lane & 15, quad = lane >> 4;
  const int qt = blockIdx.x, by = blockIdx.y;
  const int b = by >> 5, h = by & 31, kh = h >> 2;
  const int qrow0 = qt * 64 + wave * 16;

  // Q A-frags from global (scale pre-folded in gemm epilogue)
  short8 aq[4];
  const u16* qb = Q + (size_t)(b * S_ + qrow0 + l15) * 4096 + h * 128 + quad * 8;
#pragma unroll
  for (int ks = 0; ks < 4; ks++) aq[ks] = *(const short8*)(qb + ks * 32);

  floatx4 o_acc[8] = {};
  float m_i[4] = {-1e30f, -1e30f, -1e30f, -1e30f};
  float l_i[4] = {0.f, 0.f, 0.f, 0.f};
  u16* Pw = Ps + wave * 16 * 72;
  const u16* kbase = Kg + (size_t)(b * S_) * 1024 + kh * 128;
  const u16* vbase = Vtg + (size_t)(kh * 128) * 4096 + (size_t)(b * S_);

  for (int kt = 0; kt <= qt; ++kt) {
    // S = Q K^T, B-frags direct from global K
    floatx4 sc[4] = {};
#pragma unroll
    for (int nt = 0; nt < 4; nt++)
#pragma unroll
      for (int ks = 0; ks < 4; ks++) {
        short8 bk = *(const short8*)(kbase + (size_t)(kt * 64 + nt * 16 + l15) * 1024 + ks * 32 + quad * 8);
        sc[nt] = __builtin_amdgcn_mfma_f32_16x16x32_bf16(aq[ks], bk, sc[nt], 0, 0, 0);
      }

    if (kt == qt) {
#pragma unroll
      for (int nt = 0; nt < 4; nt++)
#pragma unroll
        for (int r = 0; r < 4; r++)
          if (nt * 16 + l15 > wave * 16 + quad * 4 + r) sc[nt][r] = -1e30f;
    }

    // online softmax (rows quad*4+r, 16 lanes of a quad hold 16 cols)
    float pv[4][4], alpha[4];
#pragma unroll
    for (int r = 0; r < 4; r++) {
      float mx = fmaxf(fmaxf(sc[0][r], sc[1][r]), fmaxf(sc[2][r], sc[3][r]));
#pragma unroll
      for (int off = 1; off < 16; off <<= 1) mx = fmaxf(mx, __shfl_xor(mx, off, 64));
      const float mn = fmaxf(m_i[r], mx);
      alpha[r] = __expf(m_i[r] - mn);
      m_i[r] = mn;
      float rs = 0.f;
#pragma unroll
      for (int nt = 0; nt < 4; nt++) {
        const float p = __expf(sc[nt][r] - mn);
        pv[nt][r] = p;
        rs += p;
      }
#pragma unroll
      for (int off = 1; off < 16; off <<= 1) rs += __shfl_xor(rs, off, 64);
      l_i[r] = l_i[r] * alpha[r] + rs;
    }
#pragma unroll
    for (int dt = 0; dt < 8; dt++)
#pragma unroll
      for (int r = 0; r < 4; r++) o_acc[dt][r] *= alpha[r];

    // P: C-layout -> A-layout via per-wave LDS (no barrier: same-wave in-order)
#pragma unroll
    for (int nt = 0; nt < 4; nt++)
#pragma unroll
      for (int r = 0; r < 4; r++)
        Pw[(quad * 4 + r) * 72 + nt * 16 + l15] = f32_bf16(pv[nt][r]);

    // O += P V, V^T B-frags direct from global
#pragma unroll
    for (int ks2 = 0; ks2 < 2; ks2++) {
      short8 ap = *(const short8*)(Pw + l15 * 72 + ks2 * 32 + quad * 8);
#pragma unroll
      for (int dt = 0; dt < 8; dt++) {
        short8 bv = *(const short8*)(vbase + (size_t)(dt * 16 + l15) * 4096 + kt * 64 + ks2 * 32 + quad * 8);
        o_acc[dt] = __builtin_amdgcn_mfma_f32_16x16x32_bf16(ap, bv, o_acc[dt], 0, 0, 0);
      }
    }
  }

  float inv[4];
#pragma unroll
  for (int r = 0; r < 4; r++) inv[r] = 1.f / l_i[r];
  // in-place C write: this wave wrote-only-after-reading its own Q rows/dims
#pragma unroll
  for (int dt = 0; dt < 8; dt++)
#pragma unroll
    for (int r = 0; r < 4; r++)
      Q[(size_t)(b * S_ + qrow0 + quad * 4 + r) * 4096 + h * 128 + dt * 16 + l15] =
          f32_bf16(o_acc[dt][r] * inv[r]);
}

extern "C" void kernel_launch(void* const* d_in, const int* in_sizes, int n_in,
                              void* d_out, int out_size, void* d_ws, size_t ws_size,
                              hipStream_t stream) {
  const float* hs   = (const float*)d_in[0];
  const float* cosT = (const float*)d_in[1];
  const float* sinT = (const float*)d_in[2];
  const float* Wq = (const float*)d_in[5];
  const float* Wk = (const float*)d_in[6];
  const float* Wv = (const float*)d_in[7];
  const float* Wo = (const float*)d_in[8];
  float* out = (float*)d_out;

  char* ws = (char*)d_ws;
  u16* hsB = (u16*)(ws);                        // 33.5 MB  (dead after gemm_v)
  u16* QB  = (u16*)(ws + 33554432);             // 33.5 MB  Q, then C in-place
  u16* KB  = (u16*)(ws + 67108864);             // 8.4 MB
  u16* VB  = (u16*)(ws + 75497472);             // 8.4 MB
  u16* W1  = (u16*)(ws + 83886080);             // 41.9 MB: Wq+Wk concat; later Wv / VT / WoB
  u16* WvB = W1;                                // 8.4 MB (after gemm_qk)
  u16* VT  = W1;                                // 8.4 MB (after gemm_v)
  u16* WoB = (u16*)(ws + 92274688);             // 33.5 MB (tail of W1 region)
  // total footprint: 125829120 B (same as round 2)

  dim3 blk(256);
  // hs, Wq, Wk -> bf16 (one launch)
  cvt3<<<dim3(36864), blk, 0, stream>>>(hs, Wq, Wk, (u32*)hsB, (u32*)W1);
  // fused Q+K projection, RoPE+scale epilogue
  gemm128<0><<<dim3(40, 32), blk, 0, stream>>>(hsB, W1, QB, KB, 5120, cosT, sinT);
  // V projection
  cvt1<<<dim3(4096), blk, 0, stream>>>(Wv, (u32*)WvB);
  gemm128<1><<<dim3(8, 32), blk, 0, stream>>>(hsB, WvB, VB, nullptr, 1024, cosT, sinT);
  // V -> V^T
  transp<<<dim3(16, 64), blk, 0, stream>>>(VB, VT);
  // flash attention (C in-place into QB)
  flash2<<<dim3(S_ / 64, 2 * NH_), blk, 0, stream>>>(QB, KB, VT);
  // output projection
  cvt1<<<dim3(16384), blk, 0, stream>>>(Wo, (u32*)WoB);
  gemm128<2><<<dim3(32, 32), blk, 0, stream>>>(QB, WoB, out, nullptr, 4096, cosT, sinT);
}